// Round 6
// baseline (89.756 us; speedup 1.0000x reference)
//
#include <hip/hip_runtime.h>

// Problem constants
#define Bn   4
#define Cn   64
#define Hn   96
#define Wn   96
#define Gn   4
#define CGn  16      // Cn / Gn
#define KKn  9
#define NOFF 18      // 2*K*K offset channels
#define HWn  (Hn*Wn) // 9216

// ws layout (floats)
#define OFF_BASE  0                            // B*HW*18 pos-major offsets (663552)
#define WT_BASE   (Bn*HWn*NOFF)                // wT[ci][o][k]  (10368)
#define WDT_BASE  (WT_BASE + Cn*NOFF*KKn)      // wd2[g][k][c][d] (9216)
#define XT_BASE   (WDT_BASE + Gn*KKn*CGn*CGn)  // xT[b][pos][c] NHWC (2359296)

// ---------------------------------------------------------------------------
// Kernel 0 (fused): blocks [0,576) transpose x NCHW->NHWC; blocks >=576
// reorder the two weight tensors.
// ---------------------------------------------------------------------------
#define NTRB (Bn * (HWn / 64))   // 576 transpose blocks
__global__ __launch_bounds__(256) void prep_all(
    const float* __restrict__ x, const float* __restrict__ w_off,
    const float* __restrict__ w_def, float* __restrict__ ws)
{
    __shared__ float t[64][65];
    if (blockIdx.x < NTRB) {
        const int nb = HWn / 64;               // 144
        const int b  = blockIdx.x / nb;
        const int p0 = (blockIdx.x % nb) * 64;
        float* xT = ws + XT_BASE;
        for (int i = threadIdx.x; i < 64 * 64; i += 256) {
            const int c = i >> 6, l = i & 63;
            t[c][l] = x[(b * Cn + c) * HWn + p0 + l];
        }
        __syncthreads();
        for (int i = threadIdx.x; i < 64 * 64; i += 256) {
            const int l = i >> 6, c = i & 63;
            xT[(b * HWn + p0 + l) * Cn + c] = t[c][l];
        }
        return;
    }
    const int i = (blockIdx.x - NTRB) * 256 + threadIdx.x;
    const int NT = Cn * NOFF * KKn;        // 10368
    const int ND = Gn * KKn * CGn * CGn;   // 9216
    if (i < NT) {
        const int ci = i / (NOFF * KKn);
        const int r  = i % (NOFF * KKn);
        const int o  = r / KKn, k = r % KKn;
        ws[WT_BASE + i] = w_off[(o * Cn + ci) * KKn + k];
    } else if (i < NT + ND) {
        const int j = i - NT;
        const int d = j % CGn;
        const int c = (j / CGn) % CGn;
        const int k = (j / (CGn * CGn)) % KKn;
        const int g = j / (KKn * CGn * CGn);
        ws[WDT_BASE + j] = w_def[((g * CGn + d) * CGn + c) * KKn + k];
    }
}

// ---------------------------------------------------------------------------
// Kernel 1: offset conv (64 -> 18, 3x3, pad 1), ci-split across 8 waves.
// XCD-swizzled. Writes offsets POS-MAJOR: offs[(b*HW+pos)*18 + o].
// ---------------------------------------------------------------------------
#define OCB 64
__global__ __launch_bounds__(512) void offset_conv_v3(
    const float* __restrict__ x, const float* __restrict__ ws,
    const float* __restrict__ bias, float* __restrict__ offs)
{
    __shared__ float red[8][OCB][NOFF + 1];
    const float* __restrict__ wT = ws + WT_BASE;

    // grid = 576 = 8 * 72: XCD k takes contiguous work [k*72, (k+1)*72)
    const int bid  = (blockIdx.x & 7) * 72 + (blockIdx.x >> 3);
    const int wave = threadIdx.x >> 6;
    const int lane = threadIdx.x & 63;
    const int nb   = HWn / OCB;            // 144
    const int b    = bid / nb;
    const int pbase= (bid % nb) * OCB;
    const int pos  = pbase + lane;
    const int ho = pos / Wn, wo = pos % Wn;

    float acc[NOFF];
    #pragma unroll
    for (int o = 0; o < NOFF; o++) acc[o] = 0.f;

    const float* xb = x + b * Cn * HWn;
    const int ci0 = __builtin_amdgcn_readfirstlane(wave * 8);

    for (int ci = ci0; ci < ci0 + 8; ci++) {
        const float* xc = xb + ci * HWn;
        float xv[KKn];
        #pragma unroll
        for (int ki = 0; ki < 3; ki++) {
            const int y = ho - 1 + ki;
            const bool vy = (y >= 0) && (y < Hn);
            const float* xr = xc + y * Wn;
            #pragma unroll
            for (int kj = 0; kj < 3; kj++) {
                const int xx = wo - 1 + kj;
                const bool v = vy && (xx >= 0) && (xx < Wn);
                xv[ki * 3 + kj] = v ? xr[xx] : 0.f;
            }
        }
        const float* wp = wT + ci * (NOFF * KKn);   // wave-uniform
        #pragma unroll
        for (int o = 0; o < NOFF; o++) {
            #pragma unroll
            for (int k = 0; k < KKn; k++)
                acc[o] += xv[k] * wp[o * KKn + k];
        }
    }

    #pragma unroll
    for (int o = 0; o < NOFF; o++) red[wave][lane][o] = acc[o];
    __syncthreads();

    for (int idx = threadIdx.x; idx < NOFF * OCB; idx += 512) {
        const int o = idx % NOFF;
        const int p = idx / NOFF;
        float s = bias[o];
        #pragma unroll
        for (int w2 = 0; w2 < 8; w2++) s += red[w2][p][o];
        offs[(b * HWn + pbase + p) * NOFF + o] = s;
    }
}

// ---------------------------------------------------------------------------
// Kernel 2: deformable conv from NHWC x. Block 512 = 128 pos x 4 c-chunks
// (4 channels each). Per tap per thread: 4 independent float4 gathers (the
// 4 chunks of one (pos,tap) hit the SAME 64B line). 9 waves/SIMD supplied.
// ---------------------------------------------------------------------------
__global__ __launch_bounds__(512, 4) void deform_v6(
    const float* __restrict__ ws, float* __restrict__ out)
{
    __shared__ float red[3][128][CGn + 1];   // 26112 B
    const float* __restrict__ off2 = ws + OFF_BASE;
    const float* __restrict__ wd   = ws + WDT_BASE;
    const float* __restrict__ xT   = ws + XT_BASE;

    // grid = 1152 = 8 * 144: XCD k takes work [k*144, (k+1)*144)
    const int bid = (blockIdx.x & 7) * 144 + (blockIdx.x >> 3);
    const int nb = HWn / 128;              // 72
    const int bg = bid / nb;
    const int g  = bg & (Gn - 1);
    const int b  = bg >> 2;
    const int chunk = threadIdx.x >> 7;    // 0..3, wave-uniform (wave>>1)
    const int pl    = threadIdx.x & 127;
    const int pos   = (bid % nb) * 128 + pl;
    const int ho = pos / Wn, wo = pos % Wn;

    // hoist all 9 (dy,dx) pairs
    const float2* op2 = (const float2*)(off2 + (b * HWn + pos) * NOFF);
    float2 o2[KKn];
    #pragma unroll
    for (int k = 0; k < KKn; k++) o2[k] = op2[k];

    const int c0 = __builtin_amdgcn_readfirstlane(chunk * 4);
    const float* xch = xT + (b * HWn) * Cn + g * CGn + c0;
    const float* wg  = wd + g * (KKn * CGn * CGn) + c0 * CGn;

    float acc[CGn];
    #pragma unroll
    for (int d = 0; d < CGn; d++) acc[d] = 0.f;

    #pragma unroll
    for (int k = 0; k < KKn; k++) {
        const int ki = k / 3, kj = k % 3;
        const float ysf = (float)(ho - 1 + ki) + o2[k].x;
        const float xsf = (float)(wo - 1 + kj) + o2[k].y;
        const float y0f = floorf(ysf), x0f = floorf(xsf);
        const int   y0  = (int)y0f,    x0  = (int)x0f;
        const float wy1 = ysf - y0f, wx1 = xsf - x0f;
        const float wy0 = 1.f - wy1, wx0 = 1.f - wx1;

        const bool vy0 = (y0 >= 0)  && (y0 < Hn);
        const bool vy1 = (y0 >= -1) && (y0 < Hn - 1);
        const bool vx0 = (x0 >= 0)  && (x0 < Wn);
        const bool vx1 = (x0 >= -1) && (x0 < Wn - 1);

        const int cy0 = min(max(y0,     0), Hn - 1);
        const int cy1 = min(max(y0 + 1, 0), Hn - 1);
        const int cx0 = min(max(x0,     0), Wn - 1);
        const int cx1 = min(max(x0 + 1, 0), Wn - 1);

        const float w00 = wy0 * wx0 * ((vy0 && vx0) ? 1.f : 0.f);
        const float w01 = wy0 * wx1 * ((vy0 && vx1) ? 1.f : 0.f);
        const float w10 = wy1 * wx0 * ((vy1 && vx0) ? 1.f : 0.f);
        const float w11 = wy1 * wx1 * ((vy1 && vx1) ? 1.f : 0.f);

        // 4 independent gathers: one float4 (4 channels) per corner
        const float4 v00 = *(const float4*)(xch + (cy0 * Wn + cx0) * Cn);
        const float4 v01 = *(const float4*)(xch + (cy0 * Wn + cx1) * Cn);
        const float4 v10 = *(const float4*)(xch + (cy1 * Wn + cx0) * Cn);
        const float4 v11 = *(const float4*)(xch + (cy1 * Wn + cx1) * Cn);

        float s[4];
        s[0] = w00 * v00.x + w01 * v01.x + w10 * v10.x + w11 * v11.x;
        s[1] = w00 * v00.y + w01 * v01.y + w10 * v10.y + w11 * v11.y;
        s[2] = w00 * v00.z + w01 * v01.z + w10 * v10.z + w11 * v11.z;
        s[3] = w00 * v00.w + w01 * v01.w + w10 * v10.w + w11 * v11.w;

        const float* wk = wg + k * (CGn * CGn);   // wave-uniform [c][d]
        #pragma unroll
        for (int c = 0; c < 4; c++) {
            #pragma unroll
            for (int d = 0; d < CGn; d++)
                acc[d] += s[c] * wk[c * CGn + d];
        }
    }

    if (chunk != 0) {
        #pragma unroll
        for (int d = 0; d < CGn; d++) red[chunk - 1][pl][d] = acc[d];
    }
    __syncthreads();
    if (chunk == 0) {
        float* op = out + (b * Cn + g * CGn) * HWn + pos;
        #pragma unroll
        for (int d = 0; d < CGn; d++)
            op[d * HWn] = acc[d] + red[0][pl][d] + red[1][pl][d] + red[2][pl][d];
    }
}

// ---------------------------------------------------------------------------
extern "C" void kernel_launch(void* const* d_in, const int* in_sizes, int n_in,
                              void* d_out, int out_size, void* d_ws, size_t ws_size,
                              hipStream_t stream) {
    const float* x     = (const float*)d_in[0];
    const float* w_off = (const float*)d_in[1];
    const float* b_off = (const float*)d_in[2];
    const float* w_def = (const float*)d_in[3];
    float* out = (float*)d_out;
    float* ws  = (float*)d_ws;

    const int n_prep = Cn * NOFF * KKn + Gn * KKn * CGn * CGn;  // 19584
    const int nblk = NTRB + (n_prep + 255) / 256;               // 576 + 77

    prep_all<<<nblk, 256, 0, stream>>>(x, w_off, w_def, ws);

    offset_conv_v3<<<Bn * (HWn / OCB), 512, 0, stream>>>(x, ws, b_off, ws + OFF_BASE);

    deform_v6<<<Bn * Gn * (HWn / 128), 512, 0, stream>>>(ws, out);
}

// Round 7
// 77.262 us; speedup vs baseline: 1.1617x; 1.1617x over previous
//
#include <hip/hip_runtime.h>
#include <hip/hip_bf16.h>

// Problem constants
#define Bn   4
#define Cn   64
#define Hn   96
#define Wn   96
#define Gn   4
#define CGn  16      // Cn / Gn
#define KKn  9
#define NOFF 18      // 2*K*K offset channels
#define HWn  (Hn*Wn) // 9216

// ws layout (floats)
#define OFF_BASE  0                        // B*HW*18 pos-major offsets (663552)
#define WT_BASE   (Bn*HWn*NOFF)            // wT[ci][o][k]  (10368)
#define WMF_BASE  (WT_BASE + Cn*NOFF*KKn)  // bf16 MFMA A-frag weights: 10240 bf16 = 5120 fl
#define XT_BASE   (WMF_BASE + 5120)        // xT[b][pos][c] NHWC (2359296)

typedef __attribute__((ext_vector_type(8))) short short8v;   // 8 bf16 = 4 VGPR
typedef __attribute__((ext_vector_type(4))) float f32x4;

__device__ inline short f2bs(float v) {
    __hip_bfloat16 h = __float2bfloat16(v);
    return *reinterpret_cast<short*>(&h);
}

// ---------------------------------------------------------------------------
// Kernel 0 (fused): blocks [0,576) transpose x NCHW->NHWC; rest reorder
// offset-conv weights (fp32) and pack deform weights into bf16 MFMA A-frags.
// wmf idx = (((g*5+kp)*16 + d)*4 + q)*8 + j ;  j -> (t=j&1, c=4q+(j>>1)),
// k = 2*kp + t;  value = k<9 ? w_def[g*16+d][c][k] : 0.
// ---------------------------------------------------------------------------
#define NTRB (Bn * (HWn / 64))   // 576 transpose blocks
__global__ __launch_bounds__(256) void prep_all(
    const float* __restrict__ x, const float* __restrict__ w_off,
    const float* __restrict__ w_def, float* __restrict__ ws)
{
    __shared__ float t[64][65];
    if (blockIdx.x < NTRB) {
        const int nb = HWn / 64;               // 144
        const int b  = blockIdx.x / nb;
        const int p0 = (blockIdx.x % nb) * 64;
        float* xT = ws + XT_BASE;
        for (int i = threadIdx.x; i < 64 * 64; i += 256) {
            const int c = i >> 6, l = i & 63;
            t[c][l] = x[(b * Cn + c) * HWn + p0 + l];
        }
        __syncthreads();
        for (int i = threadIdx.x; i < 64 * 64; i += 256) {
            const int l = i >> 6, c = i & 63;
            xT[(b * HWn + p0 + l) * Cn + c] = t[c][l];
        }
        return;
    }
    const int i = (blockIdx.x - NTRB) * 256 + threadIdx.x;
    const int NT = Cn * NOFF * KKn;        // 10368
    const int NW = Gn * 5 * CGn * 4 * 8;   // 10240 bf16 elements
    if (i < NT) {
        const int ci = i / (NOFF * KKn);
        const int r  = i % (NOFF * KKn);
        const int o  = r / KKn, k = r % KKn;
        ws[WT_BASE + i] = w_off[(o * Cn + ci) * KKn + k];
    } else if (i < NT + NW) {
        const int j  = i - NT;
        const int jj = j & 7;
        const int q  = (j >> 3) & 3;
        const int d  = (j >> 5) & 15;
        const int kp = (j >> 9) % 5;
        const int g  = j / 2560;
        const int tt = jj & 1;
        const int c  = 4 * q + (jj >> 1);
        const int k  = 2 * kp + tt;
        const float v = (k < KKn) ? w_def[((g * CGn + d) * CGn + c) * KKn + k] : 0.f;
        ((__hip_bfloat16*)(ws + WMF_BASE))[j] = __float2bfloat16(v);
    }
}

// ---------------------------------------------------------------------------
// Kernel 1: offset conv (64 -> 18, 3x3, pad 1), ci-split across 8 waves.
// XCD-swizzled. Writes offsets POS-MAJOR: offs[(b*HW+pos)*18 + o].
// ---------------------------------------------------------------------------
#define OCB 64
__global__ __launch_bounds__(512) void offset_conv_v3(
    const float* __restrict__ x, const float* __restrict__ ws,
    const float* __restrict__ bias, float* __restrict__ offs)
{
    __shared__ float red[8][OCB][NOFF + 1];
    const float* __restrict__ wT = ws + WT_BASE;

    const int bid  = (blockIdx.x & 7) * 72 + (blockIdx.x >> 3);
    const int wave = threadIdx.x >> 6;
    const int lane = threadIdx.x & 63;
    const int nb   = HWn / OCB;            // 144
    const int b    = bid / nb;
    const int pbase= (bid % nb) * OCB;
    const int pos  = pbase + lane;
    const int ho = pos / Wn, wo = pos % Wn;

    float acc[NOFF];
    #pragma unroll
    for (int o = 0; o < NOFF; o++) acc[o] = 0.f;

    const float* xb = x + b * Cn * HWn;
    const int ci0 = __builtin_amdgcn_readfirstlane(wave * 8);

    for (int ci = ci0; ci < ci0 + 8; ci++) {
        const float* xc = xb + ci * HWn;
        float xv[KKn];
        #pragma unroll
        for (int ki = 0; ki < 3; ki++) {
            const int y = ho - 1 + ki;
            const bool vy = (y >= 0) && (y < Hn);
            const float* xr = xc + y * Wn;
            #pragma unroll
            for (int kj = 0; kj < 3; kj++) {
                const int xx = wo - 1 + kj;
                const bool v = vy && (xx >= 0) && (xx < Wn);
                xv[ki * 3 + kj] = v ? xr[xx] : 0.f;
            }
        }
        const float* wp = wT + ci * (NOFF * KKn);   // wave-uniform
        #pragma unroll
        for (int o = 0; o < NOFF; o++) {
            #pragma unroll
            for (int k = 0; k < KKn; k++)
                acc[o] += xv[k] * wp[o * KKn + k];
        }
    }

    #pragma unroll
    for (int o = 0; o < NOFF; o++) red[wave][lane][o] = acc[o];
    __syncthreads();

    for (int idx = threadIdx.x; idx < NOFF * OCB; idx += 512) {
        const int o = idx % NOFF;
        const int p = idx / NOFF;
        float s = bias[o];
        #pragma unroll
        for (int w2 = 0; w2 < 8; w2++) s += red[w2][p][o];
        offs[(b * HWn + pbase + p) * NOFF + o] = s;
    }
}

// ---------------------------------------------------------------------------
// Kernel 2: deformable conv via MFMA. Wave = 16-pos tile of one (b,g).
// Lane l: pr = l&15 (pos / A-row d), q = l>>4 (kappa quad).
// Per tap: each lane gathers its 4-channel float4 per corner -- lanes
// {pr, pr+16, pr+32, pr+48} read adjacent 16B of the SAME 64B pixel line.
// Contraction: acc[16d x 16pos] = sum_kp A(w)[d][kappa] * B(s)[kappa][pos],
// kappa = (c = 4q+(j>>1), t = j&1), 5 MFMAs (tail zero-padded).
// ---------------------------------------------------------------------------
#define SAMPLE(K, S)                                                       \
  {                                                                        \
    const int ki = (K) / 3, kj = (K) % 3;                                  \
    const float ysf = (float)(ho - 1 + ki) + o2[K].x;                      \
    const float xsf = (float)(wo - 1 + kj) + o2[K].y;                      \
    const float y0f = floorf(ysf), x0f = floorf(xsf);                      \
    const int   y0  = (int)y0f,    x0  = (int)x0f;                         \
    const float wy1 = ysf - y0f, wx1 = xsf - x0f;                          \
    const float wy0 = 1.f - wy1, wx0 = 1.f - wx1;                          \
    const bool vy0 = (y0 >= 0)  && (y0 < Hn);                              \
    const bool vy1 = (y0 >= -1) && (y0 < Hn - 1);                          \
    const bool vx0 = (x0 >= 0)  && (x0 < Wn);                              \
    const bool vx1 = (x0 >= -1) && (x0 < Wn - 1);                          \
    const int cy0 = min(max(y0,     0), Hn - 1);                           \
    const int cy1 = min(max(y0 + 1, 0), Hn - 1);                           \
    const int cx0 = min(max(x0,     0), Wn - 1);                           \
    const int cx1 = min(max(x0 + 1, 0), Wn - 1);                           \
    const float w00 = wy0 * wx0 * ((vy0 && vx0) ? 1.f : 0.f);              \
    const float w01 = wy0 * wx1 * ((vy0 && vx1) ? 1.f : 0.f);              \
    const float w10 = wy1 * wx0 * ((vy1 && vx0) ? 1.f : 0.f);              \
    const float w11 = wy1 * wx1 * ((vy1 && vx1) ? 1.f : 0.f);              \
    const float4 v00 = *(const float4*)(xch + (cy0 * Wn + cx0) * Cn);      \
    const float4 v01 = *(const float4*)(xch + (cy0 * Wn + cx1) * Cn);      \
    const float4 v10 = *(const float4*)(xch + (cy1 * Wn + cx0) * Cn);      \
    const float4 v11 = *(const float4*)(xch + (cy1 * Wn + cx1) * Cn);      \
    S[0] = w00 * v00.x + w01 * v01.x + w10 * v10.x + w11 * v11.x;          \
    S[1] = w00 * v00.y + w01 * v01.y + w10 * v10.y + w11 * v11.y;          \
    S[2] = w00 * v00.z + w01 * v01.z + w10 * v10.z + w11 * v11.z;          \
    S[3] = w00 * v00.w + w01 * v01.w + w10 * v10.w + w11 * v11.w;          \
  }

__global__ __launch_bounds__(256) void deform_v7(
    const float* __restrict__ ws, float* __restrict__ out)
{
    const float* __restrict__ off2 = ws + OFF_BASE;
    const float* __restrict__ xT   = ws + XT_BASE;
    const short8v* __restrict__ wmf = (const short8v*)(ws + WMF_BASE);

    // grid = 2304 = 8 * 288: XCD k gets 288 consecutive work ids (2 bg)
    const int bid = (blockIdx.x & 7) * 288 + (blockIdx.x >> 3);
    const int nbb = HWn / 64;              // 144 blocks per (b,g)
    const int bg  = bid / nbb;
    const int g   = bg & (Gn - 1);
    const int b   = bg >> 2;
    const int wave = threadIdx.x >> 6;
    const int lane = threadIdx.x & 63;
    const int pr   = lane & 15;            // pos-sub (B-col) / d (A-row)
    const int q    = lane >> 4;            // kappa quad
    const int pos0 = (bid % nbb) * 64 + wave * 16;
    const int pos  = pos0 + pr;
    const int ho = pos / Wn, wo = pos % Wn;

    // hoist this pos's 9 (dy,dx)
    const float2* op2 = (const float2*)(off2 + (b * HWn + pos) * NOFF);
    float2 o2[KKn];
    #pragma unroll
    for (int k = 0; k < KKn; k++) o2[k] = op2[k];

    // preload 5 A-fragments of weights (d = pr, quad = q)
    short8v a[5];
    #pragma unroll
    for (int kp = 0; kp < 5; kp++)
        a[kp] = wmf[((g * 5 + kp) * CGn + pr) * 4 + q];

    const float* xch = xT + (b * HWn) * Cn + g * CGn + q * 4;

    f32x4 acc = {0.f, 0.f, 0.f, 0.f};

    #pragma unroll
    for (int kp = 0; kp < 5; kp++) {
        float s0[4], s1[4];
        SAMPLE(2 * kp, s0);
        if (kp < 4) {
            SAMPLE(2 * kp + 1, s1);
        } else {
            s1[0] = s1[1] = s1[2] = s1[3] = 0.f;
        }
        short8v bfr;
        bfr[0] = f2bs(s0[0]); bfr[1] = f2bs(s1[0]);
        bfr[2] = f2bs(s0[1]); bfr[3] = f2bs(s1[1]);
        bfr[4] = f2bs(s0[2]); bfr[5] = f2bs(s1[2]);
        bfr[6] = f2bs(s0[3]); bfr[7] = f2bs(s1[3]);
        acc = __builtin_amdgcn_mfma_f32_16x16x32_bf16(a[kp], bfr, acc, 0, 0, 0);
    }

    // D: col = lane&15 = pos-sub, row = q*4 + r = d
    float* op = out + (b * Cn + g * CGn) * HWn + pos0;
    #pragma unroll
    for (int r = 0; r < 4; r++) {
        const int d = q * 4 + r;
        op[d * HWn + pr] = acc[r];
    }
}

// ---------------------------------------------------------------------------
extern "C" void kernel_launch(void* const* d_in, const int* in_sizes, int n_in,
                              void* d_out, int out_size, void* d_ws, size_t ws_size,
                              hipStream_t stream) {
    const float* x     = (const float*)d_in[0];
    const float* w_off = (const float*)d_in[1];
    const float* b_off = (const float*)d_in[2];
    const float* w_def = (const float*)d_in[3];
    float* out = (float*)d_out;
    float* ws  = (float*)d_ws;

    const int n_prep = Cn * NOFF * KKn + Gn * 5 * CGn * 4 * 8;  // 20608
    const int nblk = NTRB + (n_prep + 255) / 256;               // 576 + 81

    prep_all<<<nblk, 256, 0, stream>>>(x, w_off, w_def, ws);

    offset_conv_v3<<<Bn * (HWn / OCB), 512, 0, stream>>>(x, ws, b_off, ws + OFF_BASE);

    deform_v7<<<Bn * Gn * (HWn / 64), 256, 0, stream>>>(ws, out);
}